// Round 7
// baseline (190.850 us; speedup 1.0000x reference)
//
#include <hip/hip_runtime.h>
#include <hip/hip_bf16.h>

namespace {

constexpr int kN = 8192;
constexpr float kScale = 0.35355339059327373f;  // 1/sqrt(D=8)

typedef __attribute__((ext_vector_type(8))) short short8;
typedef __attribute__((ext_vector_type(4))) float f32x4;
using uint = unsigned int;

// HW bf16 RNE: scalar casts -> compiler fuses pairs into v_cvt_pk_bf16_f32
__device__ __forceinline__ uint pack2(float lo, float hi) {
  const unsigned short a =
      __builtin_bit_cast(unsigned short, __float2bfloat16(lo));
  const unsigned short b =
      __builtin_bit_cast(unsigned short, __float2bfloat16(hi));
  return (uint)a | ((uint)b << 16);
}
__device__ __forceinline__ float sx(float v, int m) {
  return __shfl_xor(v, m, 64);
}

// WG = 256 (4 waves) owns 32 consecutive points; wave w owns points
// n0+8w..n0+8w+7 end-to-end. No barriers in the point loop.
// Register-pressure discipline (R6 post-mortem: accK+accV live together +
// prefetch = spill -> 116MB scratch): per point do K-GEMM -> softmax ->
// V-GEMM, so only ONE 32-reg accumulator array is live at a time and the
// depth-1 point prefetch (32 regs in flight) fits under the 128-reg cap.
__global__ __launch_bounds__(256, 4) void ca_mfma5(
    const float* __restrict__ pcd, const float* __restrict__ nbr,
    const float* __restrict__ q_w, const float* __restrict__ k_w,
    const float* __restrict__ v_w, float* __restrict__ out) {
  __shared__ alignas(16) ushort w_lds[2][64][64];  // [W][o][c] bf16, swizzled
  __shared__ alignas(16) float q_lds[32 * 68];     // [point][o], pre-scaled
  __shared__ alignas(16) float x_lds[32][69];      // [point][o], pitch 69

  const int t = threadIdx.x, wave = t >> 6, lane = t & 63;
  const int l15 = lane & 15, g = lane >> 4;
  const int chunk = blockIdx.x;
  const int b = chunk >> 8;  // 256 chunks per batch
  const int n0 = (chunk & 255) * 32;

  const float* nbase = nbr + (size_t)b * 16777216;  // [c][n][k], c-stride 262144

  // ---- prologue: issue this wave's first point gathers before staging ----
  float bl[2][2][8];  // [ks][nt][j]; const-indexed register array
  {
    const float* nb = nbase + (size_t)(n0 + wave * 8) * 32;
#pragma unroll
    for (int ks = 0; ks < 2; ++ks)
#pragma unroll
      for (int nt = 0; nt < 2; ++nt)
#pragma unroll
        for (int j = 0; j < 8; ++j)
          bl[ks][nt][j] =
              nb[(size_t)(ks * 32 + g * 8 + j) * 262144 + nt * 16 + l15];
  }

  // ---- stage k_w/v_w as swizzled bf16 A-tiles (1024 tasks, 4/thread) ----
#pragma unroll
  for (int it = 0; it < 4; ++it) {
    const int task = it * 256 + t;
    const int W = task >> 9, m = (task >> 3) & 63, c0 = (task & 7) * 8;
    const float* src = (W ? v_w : k_w) + m * 64 + c0;
    const float4 a = *(const float4*)src;
    const float4 c = *(const float4*)(src + 4);
    const uint4 pk = make_uint4(pack2(a.x, a.y), pack2(a.z, a.w),
                                pack2(c.x, c.y), pack2(c.z, c.w));
    *(uint4*)((char*)&w_lds[W][m][0] + ((c0 * 2) ^ ((m & 7) << 4))) = pk;
  }

  // ---- waves 0,1: q = (kScale*q_w) * pcd for 16 points each, via MFMA ----
  if (wave < 2) {
    const int np = n0 + wave * 16;
    short8 bp[2];  // B: lane l15 = point, elems = c
#pragma unroll
    for (int ks = 0; ks < 2; ++ks) {
      float pv[8];
#pragma unroll
      for (int j = 0; j < 8; ++j)
        pv[j] = pcd[((size_t)b * 64 + ks * 32 + g * 8 + j) * kN + np + l15];
      const uint4 u = make_uint4(pack2(pv[0], pv[1]), pack2(pv[2], pv[3]),
                                 pack2(pv[4], pv[5]), pack2(pv[6], pv[7]));
      bp[ks] = *(const short8*)&u;
    }
    f32x4 cq[4] = {};
#pragma unroll
    for (int ks = 0; ks < 2; ++ks) {
#pragma unroll
      for (int mt = 0; mt < 4; ++mt) {
        const float* qs = q_w + (mt * 16 + l15) * 64 + ks * 32 + g * 8;
        const float4 qa = *(const float4*)qs;
        const float4 qb = *(const float4*)(qs + 4);
        const uint4 u = make_uint4(pack2(qa.x * kScale, qa.y * kScale),
                                   pack2(qa.z * kScale, qa.w * kScale),
                                   pack2(qb.x * kScale, qb.y * kScale),
                                   pack2(qb.z * kScale, qb.w * kScale));
        const short8 aq = *(const short8*)&u;
        cq[mt] =
            __builtin_amdgcn_mfma_f32_16x16x32_bf16(aq, bp[ks], cq[mt], 0, 0, 0);
      }
    }
    // C: lane holds q[o = mt*16 + g*4 + r][point = np + l15]
#pragma unroll
    for (int mt = 0; mt < 4; ++mt)
      *(f32x4*)&q_lds[(wave * 16 + l15) * 68 + mt * 16 + g * 4] = cq[mt];
  }
  __syncthreads();  // barrier #1 (last until epilogue)

  const int swz = (l15 & 7) << 4;

  // ---- 8 points per wave; depth-1 point prefetch ----
#pragma unroll
  for (int i = 0; i < 8; ++i) {
    const int pl = wave * 8 + i;

    // pack current point's B fragments (frees bl for the prefetch below)
    short8 bf[2][2];
#pragma unroll
    for (int ks = 0; ks < 2; ++ks)
#pragma unroll
      for (int nt = 0; nt < 2; ++nt) {
        const uint4 u = make_uint4(pack2(bl[ks][nt][0], bl[ks][nt][1]),
                                   pack2(bl[ks][nt][2], bl[ks][nt][3]),
                                   pack2(bl[ks][nt][4], bl[ks][nt][5]),
                                   pack2(bl[ks][nt][6], bl[ks][nt][7]));
        bf[ks][nt] = *(const short8*)&u;
      }

    // issue next point's gathers; they fly under K-GEMM+softmax+V-GEMM+fold
    if (i < 7) {
      const float* nbn = nbase + (size_t)(n0 + pl + 1) * 32;
#pragma unroll
      for (int ks = 0; ks < 2; ++ks)
#pragma unroll
        for (int nt = 0; nt < 2; ++nt)
#pragma unroll
          for (int j = 0; j < 8; ++j)
            bl[ks][nt][j] =
                nbn[(size_t)(ks * 32 + g * 8 + j) * 262144 + nt * 16 + l15];
    }

    // ---- K projection GEMM only (accK is the sole live accumulator) ----
    f32x4 accK[2][4] = {};
    __builtin_amdgcn_s_setprio(1);
#pragma unroll
    for (int ks = 0; ks < 2; ++ks)
#pragma unroll
      for (int mt = 0; mt < 4; ++mt) {
        const short8 af = *(const short8*)(
            (const char*)&w_lds[0][mt * 16 + l15][0] + ((ks * 64 + g * 16) ^ swz));
#pragma unroll
        for (int nt = 0; nt < 2; ++nt)
          accK[nt][mt] = __builtin_amdgcn_mfma_f32_16x16x32_bf16(
              af, bf[ks][nt], accK[nt][mt], 0, 0, 0);
      }
    __builtin_amdgcn_s_setprio(0);

    // C layout: lane holds C[m = mt*16 + g*4 + r][k = nt*16 + l15]
    // energy + exp (no max-sub: unit-normal inputs keep |e| small)
    float p_[4][2], ps[4];
#pragma unroll
    for (int mt = 0; mt < 4; ++mt) {
      const f32x4 qv = *(const f32x4*)&q_lds[pl * 68 + mt * 16 + g * 4];
#pragma unroll
      for (int nt = 0; nt < 2; ++nt) {
        float part = qv.x * accK[nt][mt][0] + qv.y * accK[nt][mt][1] +
                     qv.z * accK[nt][mt][2] + qv.w * accK[nt][mt][3];
        p_[mt][nt] = __expf(part + sx(part, 16));  // d-halves meet at g^1
      }
      ps[mt] = p_[mt][0] + p_[mt][1];
    }
    // accK dead from here -> accV below reuses its registers

    // denominator fold: 4 sums over 16 lanes; lane ends with its head's sum
    const bool b8 = (l15 & 8) != 0, b4 = (l15 & 4) != 0;
    float s0 = (b8 ? ps[2] : ps[0]) + sx(b8 ? ps[0] : ps[2], 8);
    float s1 = (b8 ? ps[3] : ps[1]) + sx(b8 ? ps[1] : ps[3], 8);
    float sm = (b4 ? s1 : s0) + sx(b4 ? s0 : s1, 4);
    sm += sx(sm, 2);
    sm += sx(sm, 1);

    // ---- V projection GEMM (reuses the accumulator registers) ----
    f32x4 accV[2][4] = {};
    __builtin_amdgcn_s_setprio(1);
#pragma unroll
    for (int ks = 0; ks < 2; ++ks)
#pragma unroll
      for (int mt = 0; mt < 4; ++mt) {
        const short8 af = *(const short8*)(
            (const char*)&w_lds[1][mt * 16 + l15][0] + ((ks * 64 + g * 16) ^ swz));
#pragma unroll
        for (int nt = 0; nt < 2; ++nt)
          accV[nt][mt] = __builtin_amdgcn_mfma_f32_16x16x32_bf16(
              af, bf[ks][nt], accV[nt][mt], 0, 0, 0);
      }
    __builtin_amdgcn_s_setprio(0);

    // PV (unnormalized) then 16->1 fold
    float xv[16];
#pragma unroll
    for (int mt = 0; mt < 4; ++mt)
#pragma unroll
      for (int r = 0; r < 4; ++r)
        xv[mt * 4 + r] =
            p_[mt][0] * accV[0][mt][r] + p_[mt][1] * accV[1][mt][r];
    float a8[8];
#pragma unroll
    for (int j = 0; j < 8; ++j)
      a8[j] = (b8 ? xv[j + 8] : xv[j]) + sx(b8 ? xv[j] : xv[j + 8], 8);
    float a4[4];
#pragma unroll
    for (int j = 0; j < 4; ++j)
      a4[j] = (b4 ? a8[j + 4] : a8[j]) + sx(b4 ? a8[j] : a8[j + 4], 4);
    const bool b2 = (l15 & 2) != 0, b1 = (l15 & 1) != 0;
    float a2[2];
#pragma unroll
    for (int j = 0; j < 2; ++j)
      a2[j] = (b2 ? a4[j + 2] : a4[j]) + sx(b2 ? a4[j] : a4[j + 2], 2);
    const float x1 = (b1 ? a2[1] : a2[0]) + sx(b1 ? a2[0] : a2[1], 1);

    // lane holds x[m=(l15>>2)*16+g*4+(l15&3)]; wave-private row, no barrier
    x_lds[pl][(l15 >> 2) * 16 + g * 4 + (l15 & 3)] =
        x1 * __builtin_amdgcn_rcpf(sm);
  }

  __syncthreads();  // barrier #2: cross-wave output transpose

  // ---- epilogue: full-line stores; (o,seg) -> float4 over n; 2 per thread --
#pragma unroll
  for (int it = 0; it < 2; ++it) {
    const int task = it * 256 + t;
    const int o = task >> 3, seg = task & 7;
    float4 r;
    r.x = x_lds[seg * 4 + 0][o];
    r.y = x_lds[seg * 4 + 1][o];
    r.z = x_lds[seg * 4 + 2][o];
    r.w = x_lds[seg * 4 + 3][o];
    *(float4*)&out[((size_t)b * 64 + o) * kN + n0 + seg * 4] = r;
  }
}

}  // namespace

extern "C" void kernel_launch(void* const* d_in, const int* in_sizes, int n_in,
                              void* d_out, int out_size, void* d_ws,
                              size_t ws_size, hipStream_t stream) {
  const float* pcd = (const float*)d_in[0];
  const float* nbr = (const float*)d_in[1];
  const float* q_w = (const float*)d_in[2];
  const float* k_w = (const float*)d_in[3];
  const float* v_w = (const float*)d_in[4];
  float* out = (float*)d_out;

  const dim3 grid(1024);  // 32768 points / 32 per WG
  const dim3 block(256);
  hipLaunchKernelGGL(ca_mfma5, grid, block, 0, stream, pcd, nbr, q_w, k_w, v_w,
                     out);
}

// Round 8
// 79.775 us; speedup vs baseline: 2.3924x; 2.3924x over previous
//
#include <hip/hip_runtime.h>
#include <hip/hip_bf16.h>

namespace {

constexpr int kN = 8192;
constexpr float kScale = 0.35355339059327373f;  // 1/sqrt(D=8)

typedef __attribute__((ext_vector_type(8))) short short8;
typedef __attribute__((ext_vector_type(4))) float f32x4;
using uint = unsigned int;

// HW bf16 RNE: scalar casts -> compiler fuses pairs into v_cvt_pk_bf16_f32
__device__ __forceinline__ uint pack2(float lo, float hi) {
  const unsigned short a =
      __builtin_bit_cast(unsigned short, __float2bfloat16(lo));
  const unsigned short b =
      __builtin_bit_cast(unsigned short, __float2bfloat16(hi));
  return (uint)a | ((uint)b << 16);
}
__device__ __forceinline__ float sx(float v, int m) {
  return __shfl_xor(v, m, 64);
}

// WG = 256 (4 waves) owns 32 consecutive points; wave w owns points
// n0+8w..n0+8w+7. Two barriers TOTAL (post-staging, pre-epilogue); the point
// loop is barrier-free (x rows are wave-private).
// Register discipline (R5-R7 post-mortems): NO cross-point register prefetch.
// With MFMA the allocator splits 128 unified regs as 64 VGPR + 64 AGPR
// (accK+accV); a 32-reg prefetch array on top of bf+temps spills -> 100-300MB
// scratch traffic. R4's no-prefetch envelope is the proven fit; we instead
// split the in-point wait by K-half (pack+GEMM ks0 while ks1 loads fly) and
// let the unrolled, barrier-free loop give the scheduler freedom to hoist
// next-point loads where registers allow.
__global__ __launch_bounds__(256, 4) void ca_mfma6(
    const float* __restrict__ pcd, const float* __restrict__ nbr,
    const float* __restrict__ q_w, const float* __restrict__ k_w,
    const float* __restrict__ v_w, float* __restrict__ out) {
  __shared__ alignas(16) ushort w_lds[2][64][64];  // [W][o][c] bf16, swizzled
  __shared__ alignas(16) float q_lds[32 * 68];     // [point][o], pre-scaled
  __shared__ alignas(16) float x_lds[32][69];      // [point][o], pitch 69

  const int t = threadIdx.x, wave = t >> 6, lane = t & 63;
  const int l15 = lane & 15, g = lane >> 4;
  const int chunk = blockIdx.x;
  const int b = chunk >> 8;  // 256 chunks per batch
  const int n0 = (chunk & 255) * 32;

  const float* nbase = nbr + (size_t)b * 16777216;  // [c][n][k], c-stride 262144

  // ---- stage k_w/v_w as swizzled bf16 A-tiles (1024 tasks, 4/thread) ----
#pragma unroll
  for (int it = 0; it < 4; ++it) {
    const int task = it * 256 + t;
    const int W = task >> 9, m = (task >> 3) & 63, c0 = (task & 7) * 8;
    const float* src = (W ? v_w : k_w) + m * 64 + c0;
    const float4 a = *(const float4*)src;
    const float4 c = *(const float4*)(src + 4);
    const uint4 pk = make_uint4(pack2(a.x, a.y), pack2(a.z, a.w),
                                pack2(c.x, c.y), pack2(c.z, c.w));
    *(uint4*)((char*)&w_lds[W][m][0] + ((c0 * 2) ^ ((m & 7) << 4))) = pk;
  }

  // ---- waves 0,1: q = (kScale*q_w) * pcd for 16 points each, via MFMA ----
  if (wave < 2) {
    const int np = n0 + wave * 16;
    short8 bp[2];  // B: lane l15 = point, elems = c
#pragma unroll
    for (int ks = 0; ks < 2; ++ks) {
      float pv[8];
#pragma unroll
      for (int j = 0; j < 8; ++j)
        pv[j] = pcd[((size_t)b * 64 + ks * 32 + g * 8 + j) * kN + np + l15];
      const uint4 u = make_uint4(pack2(pv[0], pv[1]), pack2(pv[2], pv[3]),
                                 pack2(pv[4], pv[5]), pack2(pv[6], pv[7]));
      bp[ks] = *(const short8*)&u;
    }
    f32x4 cq[4] = {};
#pragma unroll
    for (int ks = 0; ks < 2; ++ks) {
#pragma unroll
      for (int mt = 0; mt < 4; ++mt) {
        const float* qs = q_w + (mt * 16 + l15) * 64 + ks * 32 + g * 8;
        const float4 qa = *(const float4*)qs;
        const float4 qb = *(const float4*)(qs + 4);
        const uint4 u = make_uint4(pack2(qa.x * kScale, qa.y * kScale),
                                   pack2(qa.z * kScale, qa.w * kScale),
                                   pack2(qb.x * kScale, qb.y * kScale),
                                   pack2(qb.z * kScale, qb.w * kScale));
        const short8 aq = *(const short8*)&u;
        cq[mt] =
            __builtin_amdgcn_mfma_f32_16x16x32_bf16(aq, bp[ks], cq[mt], 0, 0, 0);
      }
    }
    // C: lane holds q[o = mt*16 + g*4 + r][point = np + l15]
#pragma unroll
    for (int mt = 0; mt < 4; ++mt)
      *(f32x4*)&q_lds[(wave * 16 + l15) * 68 + mt * 16 + g * 4] = cq[mt];
  }
  __syncthreads();  // barrier #1 (last until epilogue)

  const int swz = (l15 & 7) << 4;

  // ---- 8 points per wave; ks-split wait order, no in-loop barriers ----
#pragma unroll
  for (int i = 0; i < 8; ++i) {
    const int pl = wave * 8 + i;
    const float* nb = nbase + (size_t)(n0 + pl) * 32;

    // issue all 32 gathers; bl0 first so its vmcnt clears early
    float bl0[2][8], bl1[2][8];  // [nt][j], const-indexed register arrays
#pragma unroll
    for (int nt = 0; nt < 2; ++nt)
#pragma unroll
      for (int j = 0; j < 8; ++j)
        bl0[nt][j] = nb[(size_t)(g * 8 + j) * 262144 + nt * 16 + l15];
#pragma unroll
    for (int nt = 0; nt < 2; ++nt)
#pragma unroll
      for (int j = 0; j < 8; ++j)
        bl1[nt][j] = nb[(size_t)(32 + g * 8 + j) * 262144 + nt * 16 + l15];

    f32x4 accK[2][4] = {};
    f32x4 accV[2][4] = {};

    // ---- ks = 0: pack + K/V GEMMs (ks=1 loads still in flight) ----
    __builtin_amdgcn_s_setprio(1);
    {
      short8 bf[2];
#pragma unroll
      for (int nt = 0; nt < 2; ++nt) {
        const uint4 u = make_uint4(pack2(bl0[nt][0], bl0[nt][1]),
                                   pack2(bl0[nt][2], bl0[nt][3]),
                                   pack2(bl0[nt][4], bl0[nt][5]),
                                   pack2(bl0[nt][6], bl0[nt][7]));
        bf[nt] = *(const short8*)&u;
      }
#pragma unroll
      for (int W = 0; W < 2; ++W)
#pragma unroll
        for (int mt = 0; mt < 4; ++mt) {
          const short8 af = *(const short8*)(
              (const char*)&w_lds[W][mt * 16 + l15][0] + ((g * 16) ^ swz));
#pragma unroll
          for (int nt = 0; nt < 2; ++nt) {
            f32x4& acc = W ? accV[nt][mt] : accK[nt][mt];
            acc =
                __builtin_amdgcn_mfma_f32_16x16x32_bf16(af, bf[nt], acc, 0, 0, 0);
          }
        }
    }
    // ---- ks = 1 ----
    {
      short8 bf[2];
#pragma unroll
      for (int nt = 0; nt < 2; ++nt) {
        const uint4 u = make_uint4(pack2(bl1[nt][0], bl1[nt][1]),
                                   pack2(bl1[nt][2], bl1[nt][3]),
                                   pack2(bl1[nt][4], bl1[nt][5]),
                                   pack2(bl1[nt][6], bl1[nt][7]));
        bf[nt] = *(const short8*)&u;
      }
#pragma unroll
      for (int W = 0; W < 2; ++W)
#pragma unroll
        for (int mt = 0; mt < 4; ++mt) {
          const short8 af = *(const short8*)(
              (const char*)&w_lds[W][mt * 16 + l15][0] + ((64 + g * 16) ^ swz));
#pragma unroll
          for (int nt = 0; nt < 2; ++nt) {
            f32x4& acc = W ? accV[nt][mt] : accK[nt][mt];
            acc =
                __builtin_amdgcn_mfma_f32_16x16x32_bf16(af, bf[nt], acc, 0, 0, 0);
          }
        }
    }
    __builtin_amdgcn_s_setprio(0);

    // C layout: lane holds C[m = mt*16 + g*4 + r][k = nt*16 + l15]
    // energy + exp (no max-sub: unit-normal inputs keep |e| small; exact math)
    float p_[4][2], ps[4];
#pragma unroll
    for (int mt = 0; mt < 4; ++mt) {
      const f32x4 qv = *(const f32x4*)&q_lds[pl * 68 + mt * 16 + g * 4];
#pragma unroll
      for (int nt = 0; nt < 2; ++nt) {
        float part = qv.x * accK[nt][mt][0] + qv.y * accK[nt][mt][1] +
                     qv.z * accK[nt][mt][2] + qv.w * accK[nt][mt][3];
        p_[mt][nt] = __expf(part + sx(part, 16));  // d-halves meet at g^1
      }
      ps[mt] = p_[mt][0] + p_[mt][1];
    }

    // denominator fold: 4 sums over 16 lanes; lane ends with its head's sum
    const bool b8 = (l15 & 8) != 0, b4 = (l15 & 4) != 0;
    float s0 = (b8 ? ps[2] : ps[0]) + sx(b8 ? ps[0] : ps[2], 8);
    float s1 = (b8 ? ps[3] : ps[1]) + sx(b8 ? ps[1] : ps[3], 8);
    float sm = (b4 ? s1 : s0) + sx(b4 ? s0 : s1, 4);
    sm += sx(sm, 2);
    sm += sx(sm, 1);

    // PV (unnormalized) then 16->1 fold
    float xv[16];
#pragma unroll
    for (int mt = 0; mt < 4; ++mt)
#pragma unroll
      for (int r = 0; r < 4; ++r)
        xv[mt * 4 + r] =
            p_[mt][0] * accV[0][mt][r] + p_[mt][1] * accV[1][mt][r];
    float a8[8];
#pragma unroll
    for (int j = 0; j < 8; ++j)
      a8[j] = (b8 ? xv[j + 8] : xv[j]) + sx(b8 ? xv[j] : xv[j + 8], 8);
    float a4[4];
#pragma unroll
    for (int j = 0; j < 4; ++j)
      a4[j] = (b4 ? a8[j + 4] : a8[j]) + sx(b4 ? a8[j] : a8[j + 4], 4);
    const bool b2 = (l15 & 2) != 0, b1 = (l15 & 1) != 0;
    float a2[2];
#pragma unroll
    for (int j = 0; j < 2; ++j)
      a2[j] = (b2 ? a4[j + 2] : a4[j]) + sx(b2 ? a4[j] : a4[j + 2], 2);
    const float x1 = (b1 ? a2[1] : a2[0]) + sx(b1 ? a2[0] : a2[1], 1);

    // lane holds x[m=(l15>>2)*16+g*4+(l15&3)]; wave-private row, no barrier
    x_lds[pl][(l15 >> 2) * 16 + g * 4 + (l15 & 3)] =
        x1 * __builtin_amdgcn_rcpf(sm);
  }

  __syncthreads();  // barrier #2: cross-wave output transpose

  // ---- epilogue: full-line stores; (o,seg) -> float4 over n; 2/thread ----
#pragma unroll
  for (int it = 0; it < 2; ++it) {
    const int task = it * 256 + t;
    const int o = task >> 3, seg = task & 7;
    float4 r;
    r.x = x_lds[seg * 4 + 0][o];
    r.y = x_lds[seg * 4 + 1][o];
    r.z = x_lds[seg * 4 + 2][o];
    r.w = x_lds[seg * 4 + 3][o];
    *(float4*)&out[((size_t)b * 64 + o) * kN + n0 + seg * 4] = r;
  }
}

}  // namespace

extern "C" void kernel_launch(void* const* d_in, const int* in_sizes, int n_in,
                              void* d_out, int out_size, void* d_ws,
                              size_t ws_size, hipStream_t stream) {
  const float* pcd = (const float*)d_in[0];
  const float* nbr = (const float*)d_in[1];
  const float* q_w = (const float*)d_in[2];
  const float* k_w = (const float*)d_in[3];
  const float* v_w = (const float*)d_in[4];
  float* out = (float*)d_out;

  const dim3 grid(1024);  // 32768 points / 32 per WG
  const dim3 block(256);
  hipLaunchKernelGGL(ca_mfma6, grid, block, 0, stream, pcd, nbr, q_w, k_w, v_w,
                     out);
}